// Round 1
// baseline (73.106 us; speedup 1.0000x reference)
//
#include <hip/hip_runtime.h>
#include <math.h>

// QPU layer: quaternion power + chained Hamilton product + normalize.
// x: (P, 4*C_IN) as [r|i|j|k], weight: (C_OUT, C_IN), bias: (C_OUT)
// out: (P, 4*C_OUT) as [r|i|j|k]

#define C_IN   64
#define C_OUT  128
#define POS_PER_BLOCK 2
#define BLOCK  (POS_PER_BLOCK * C_OUT)   // 256 threads = 4 waves
#define WT_STRIDE (C_OUT + 1)            // 129: breaks pow-2 bank stride

__global__ __launch_bounds__(BLOCK, 4) void qpu_kernel(
    const float* __restrict__ x,
    const float* __restrict__ weight,
    const float* __restrict__ bias,
    float* __restrict__ out,
    int P)
{
    // transposed weight: w_t[c][o] at c*WT_STRIDE + o  (~33 KB)
    __shared__ float  w_t[C_IN * WT_STRIDE];
    // per-position precompute: (theta0, i/n, j/n, k/n) per c  (2 KB)
    __shared__ float4 pre[POS_PER_BLOCK][C_IN];

    const int tid = threadIdx.x;

    // ---- stage weight transposed into LDS ----
    // idx = o*64 + c  (coalesced global read); write w_t[c*129+o]:
    // lanes share o, c=tid%64 varies -> banks (129c+o)%32 cycle -> <=2-way.
    for (int idx = tid; idx < C_OUT * C_IN; idx += BLOCK) {
        const int o = idx >> 6;
        const int c = idx & 63;
        w_t[c * WT_STRIDE + o] = weight[idx];
    }

    const int sub = tid >> 7;        // which position within block
    const int o   = tid & 127;       // output channel
    const int pos = blockIdx.x * POS_PER_BLOCK + sub;
    const bool valid = (pos < P);

    // ---- per-position preprocessing (threads o<64 of each sub) ----
    if (valid && o < C_IN) {
        const int c = o;
        const float* xb = x + (size_t)pos * (4 * C_IN);
        const float r = xb[c];
        const float i = xb[C_IN + c];
        const float j = xb[2 * C_IN + c];
        const float k = xb[3 * C_IN + c];
        const float rc = fminf(fmaxf(r, -0.999999f), 0.999999f); // CLAMP = 1-1e-6
        const float th0 = acosf(rc);
        const float inv = rsqrtf(fmaf(i, i, fmaf(j, j, fmaf(k, k, 1e-12f))));
        pre[sub][c] = make_float4(th0, i * inv, j * inv, k * inv);
    }
    __syncthreads();

    if (!valid) return;

    const float b_o = bias[o];

    // left-fold Hamilton product (associative == reference tree reduction)
    float pr = 1.0f, pi = 0.0f, pj = 0.0f, pk = 0.0f;

    #pragma unroll 4
    for (int c = 0; c < C_IN; ++c) {
        const float4 p4 = pre[sub][c];          // LDS broadcast (same addr/wave)
        const float  w  = w_t[c * WT_STRIDE + o]; // consecutive lanes -> no conflict
        const float  th = fmaf(w, p4.x, b_o);
        float s, ct;
        __sincosf(th, &s, &ct);
        const float qr = ct;
        const float qi = p4.y * s;
        const float qj = p4.z * s;
        const float qk = p4.w * s;
        // p = p (x) q   (Hamilton, p on the left)
        const float nr = pr * qr - pi * qi - pj * qj - pk * qk;
        const float ni = pr * qi + pi * qr + pj * qk - pk * qj;
        const float nj = pr * qj - pi * qk + pj * qr + pk * qi;
        const float nk = pr * qk + pi * qj - pj * qi + pk * qr;
        pr = nr; pi = ni; pj = nj; pk = nk;
    }

    const float invn = rsqrtf(fmaf(pr, pr, fmaf(pi, pi, fmaf(pj, pj, fmaf(pk, pk, 1e-12f)))));
    float* ob = out + (size_t)pos * (4 * C_OUT);
    ob[o]             = pr * invn;   // lanes o consecutive -> coalesced
    ob[C_OUT + o]     = pi * invn;
    ob[2 * C_OUT + o] = pj * invn;
    ob[3 * C_OUT + o] = pk * invn;
}

extern "C" void kernel_launch(void* const* d_in, const int* in_sizes, int n_in,
                              void* d_out, int out_size, void* d_ws, size_t ws_size,
                              hipStream_t stream) {
    const float* x      = (const float*)d_in[0];
    const float* weight = (const float*)d_in[1];
    const float* bias   = (const float*)d_in[2];
    float* out          = (float*)d_out;

    const int P = in_sizes[0] / (4 * C_IN);   // B*T = 2048
    const int grid = (P + POS_PER_BLOCK - 1) / POS_PER_BLOCK;

    qpu_kernel<<<grid, BLOCK, 0, stream>>>(x, weight, bias, out, P);
}

// Round 2
// 72.278 us; speedup vs baseline: 1.0115x; 1.0115x over previous
//
#include <hip/hip_runtime.h>
#include <math.h>

// QPU layer: quaternion power + chained Hamilton product + normalize.
// x: (P, 4*C_IN) as [r|i|j|k], weight: (C_OUT, C_IN), bias: (C_OUT)
// out: (P, 4*C_OUT) as [r|i|j|k]

#define C_IN   64
#define C_OUT  128
#define POS_PER_BLOCK 4
#define BLOCK  (POS_PER_BLOCK * C_OUT)   // 512 threads = 8 waves
#define WT_STRIDE (C_OUT + 1)            // 129: breaks pow-2 bank stride

#define INV_2PI 0.15915494309189535f

__global__ __launch_bounds__(BLOCK, 4) void qpu_kernel(
    const float* __restrict__ x,
    const float* __restrict__ weight,
    const float* __restrict__ bias,
    float* __restrict__ out,
    int P)
{
    // transposed weight: w_t[c][o] at c*WT_STRIDE + o  (~33 KB)
    __shared__ float  w_t[C_IN * WT_STRIDE];
    // per-position precompute: (theta0, i/n, j/n, k/n) per c  (4 KB)
    __shared__ float4 pre[POS_PER_BLOCK][C_IN];

    const int tid = threadIdx.x;

    // ---- stage weight transposed into LDS, float4 loads ----
    // weight flat [o][c]; float4 idx: o = idx>>4, c0 = (idx&15)*4.
    // ds_write banks: (c+o)%32 pattern -> 2-way aliasing (free, m136).
    {
        const float4* w4 = (const float4*)weight;
        #pragma unroll
        for (int idx = tid; idx < (C_OUT * C_IN) / 4; idx += BLOCK) {
            const float4 v = w4[idx];
            const int o  = idx >> 4;
            const int c0 = (idx & 15) * 4;
            w_t[(c0 + 0) * WT_STRIDE + o] = v.x;
            w_t[(c0 + 1) * WT_STRIDE + o] = v.y;
            w_t[(c0 + 2) * WT_STRIDE + o] = v.z;
            w_t[(c0 + 3) * WT_STRIDE + o] = v.w;
        }
    }

    const int sub = tid >> 7;        // position within block (0..3)
    const int o   = tid & 127;       // output channel
    const int pos = blockIdx.x * POS_PER_BLOCK + sub;
    const bool valid = (pos < P);

    // ---- per-position preprocessing (threads o<64 of each sub) ----
    if (valid && o < C_IN) {
        const int c = o;
        const float* xb = x + (size_t)pos * (4 * C_IN);
        const float r = xb[c];
        const float i = xb[C_IN + c];
        const float j = xb[2 * C_IN + c];
        const float k = xb[3 * C_IN + c];
        const float rc = fminf(fmaxf(r, -0.999999f), 0.999999f); // CLAMP = 1-1e-6
        const float th0 = acosf(rc);
        const float inv = rsqrtf(fmaf(i, i, fmaf(j, j, fmaf(k, k, 1e-12f))));
        pre[sub][c] = make_float4(th0, i * inv, j * inv, k * inv);
    }
    __syncthreads();

    if (!valid) return;

    const float b_o = bias[o] * INV_2PI;   // fold bias into revolution domain

    // left-fold Hamilton product (associative == reference tree reduction)
    float pr = 1.0f, pi = 0.0f, pj = 0.0f, pk = 0.0f;

    #pragma unroll 8
    for (int c = 0; c < C_IN; ++c) {
        const float4 p4 = pre[sub][c];            // uniform addr -> LDS broadcast
        const float  w  = w_t[c * WT_STRIDE + o]; // consecutive lanes -> conflict-free
        // theta in revolutions: (w*th0 + b) / 2pi ; |rev| < 0.25 -> v_sin/v_cos safe
        const float rev = fmaf(w * INV_2PI, p4.x, b_o);
        const float s  = __builtin_amdgcn_sinf(rev);   // v_sin_f32: sin(rev*2pi)
        const float ct = __builtin_amdgcn_cosf(rev);   // v_cos_f32
        const float qr = ct;
        const float qi = p4.y * s;
        const float qj = p4.z * s;
        const float qk = p4.w * s;
        // p = p (x) q   (Hamilton, p on the left)
        const float nr = pr * qr - pi * qi - pj * qj - pk * qk;
        const float ni = pr * qi + pi * qr + pj * qk - pk * qj;
        const float nj = pr * qj - pi * qk + pj * qr + pk * qi;
        const float nk = pr * qk + pi * qj - pj * qi + pk * qr;
        pr = nr; pi = ni; pj = nj; pk = nk;
    }

    const float invn = rsqrtf(fmaf(pr, pr, fmaf(pi, pi, fmaf(pj, pj, fmaf(pk, pk, 1e-12f)))));
    float* ob = out + (size_t)pos * (4 * C_OUT);
    ob[o]             = pr * invn;   // lanes o consecutive -> coalesced
    ob[C_OUT + o]     = pi * invn;
    ob[2 * C_OUT + o] = pj * invn;
    ob[3 * C_OUT + o] = pk * invn;
}

extern "C" void kernel_launch(void* const* d_in, const int* in_sizes, int n_in,
                              void* d_out, int out_size, void* d_ws, size_t ws_size,
                              hipStream_t stream) {
    const float* x      = (const float*)d_in[0];
    const float* weight = (const float*)d_in[1];
    const float* bias   = (const float*)d_in[2];
    float* out          = (float*)d_out;

    const int P = in_sizes[0] / (4 * C_IN);   // B*T = 2048
    const int grid = (P + POS_PER_BLOCK - 1) / POS_PER_BLOCK;

    qpu_kernel<<<grid, BLOCK, 0, stream>>>(x, weight, bias, out, P);
}

// Round 3
// 67.395 us; speedup vs baseline: 1.0847x; 1.0724x over previous
//
#include <hip/hip_runtime.h>
#include <math.h>

// QPU layer: quaternion power + chained Hamilton product + normalize.
// x: (P, 4*C_IN) as [r|i|j|k], weight: (C_OUT, C_IN), bias: (C_OUT)
// out: (P, 4*C_OUT) as [r|i|j|k]
//
// Round 3: packed-FP32 version. Each thread computes TWO output chains
// (o = 2*lane, 2*lane+1) using <2 x float> arithmetic -> v_pk_fma_f32 /
// v_pk_mul_f32 on gfx950. One wave = one position x 128 outputs.

typedef float v2f __attribute__((ext_vector_type(2)));

#define C_IN   64
#define C_OUT  128
#define POS_PER_BLOCK 4
#define BLOCK  (POS_PER_BLOCK * 64)      // 256 threads = 4 waves, 1 wave/position
#define WSTR2  (C_OUT / 2 + 1)           // float2 row stride 65 (8B-aligned, odd -> no pow2 bank stride)

#define INV_2PI 0.15915494309189535f

__global__ __launch_bounds__(BLOCK, 2) void qpu_kernel(
    const float* __restrict__ x,
    const float* __restrict__ weight,
    const float* __restrict__ bias,
    float* __restrict__ out,
    int P)
{
    // weight transposed, float2 elements: w2[c*WSTR2 + l] = {W[2l][c], W[2l+1][c]}
    __shared__ float  w_s[C_IN * WSTR2 * 2];          // ~33.3 KB, float view for staging
    __shared__ float4 pre[POS_PER_BLOCK][C_IN];       // (theta0, i/n, j/n, k/n)  4 KB

    const int tid  = threadIdx.x;
    const int lane = tid & 63;
    const int sub  = tid >> 6;           // wave id == position within block

    // ---- stage weight transposed into LDS (float4 global loads) ----
    // weight flat [o][c]; float index in w_s for (c,o) is c*(2*WSTR2) + o = c*130 + o.
    {
        const float4* w4 = (const float4*)weight;
        #pragma unroll
        for (int idx = tid; idx < (C_OUT * C_IN) / 4; idx += BLOCK) {
            const float4 v = w4[idx];
            const int o  = idx >> 4;
            const int c0 = (idx & 15) * 4;
            w_s[(c0 + 0) * (2 * WSTR2) + o] = v.x;
            w_s[(c0 + 1) * (2 * WSTR2) + o] = v.y;
            w_s[(c0 + 2) * (2 * WSTR2) + o] = v.z;
            w_s[(c0 + 3) * (2 * WSTR2) + o] = v.w;
        }
    }

    const int pos = blockIdx.x * POS_PER_BLOCK + sub;
    const bool valid = (pos < P);

    // ---- per-position preprocessing: all 64 lanes of each wave, one channel each ----
    if (valid) {
        const int c = lane;
        const float* xb = x + (size_t)pos * (4 * C_IN);
        const float r = xb[c];
        const float i = xb[C_IN + c];
        const float j = xb[2 * C_IN + c];
        const float k = xb[3 * C_IN + c];
        const float rc = fminf(fmaxf(r, -0.999999f), 0.999999f);   // CLAMP = 1-1e-6
        const float th0 = acosf(rc);
        const float inv = rsqrtf(fmaf(i, i, fmaf(j, j, fmaf(k, k, 1e-12f))));
        pre[sub][c] = make_float4(th0, i * inv, j * inv, k * inv);
    }
    __syncthreads();

    if (!valid) return;

    // bias pair for (2*lane, 2*lane+1), folded to revolution domain
    const v2f b2 = ((const v2f*)bias)[lane] * INV_2PI;
    const v2f* __restrict__ w2 = (const v2f*)w_s;

    // two packed left-fold Hamilton chains
    v2f pr = 1.0f, pi = 0.0f, pj = 0.0f, pk = 0.0f;

    #pragma unroll 8
    for (int c = 0; c < C_IN; ++c) {
        const float4 p4 = pre[sub][c];            // wave-uniform addr -> LDS broadcast
        const v2f    w  = w2[c * WSTR2 + lane];   // ds_read_b64, conflict-free
        const float  thr = p4.x * INV_2PI;
        const v2f    rev = w * thr + b2;          // -> v_pk_fma (|rev| < 0.25)
        v2f s, ct;
        s.x  = __builtin_amdgcn_sinf(rev.x);      // v_sin_f32: sin(rev * 2pi)
        s.y  = __builtin_amdgcn_sinf(rev.y);
        ct.x = __builtin_amdgcn_cosf(rev.x);
        ct.y = __builtin_amdgcn_cosf(rev.y);
        const v2f qi = p4.y * s;                  // v_pk_mul
        const v2f qj = p4.z * s;
        const v2f qk = p4.w * s;
        // p = p (x) q  (Hamilton, p on the left) — all packed mul/fma
        const v2f nr = pr * ct - pi * qi - pj * qj - pk * qk;
        const v2f ni = pr * qi + pi * ct + pj * qk - pk * qj;
        const v2f nj = pr * qj - pi * qk + pj * ct + pk * qi;
        const v2f nk = pr * qk + pi * qj - pj * qi + pk * ct;
        pr = nr; pi = ni; pj = nj; pk = nk;
    }

    // packed normalize
    const v2f n2 = pr * pr + pi * pi + pj * pj + pk * pk + 1e-12f;
    v2f invn;
    invn.x = rsqrtf(n2.x);
    invn.y = rsqrtf(n2.y);
    pr *= invn; pi *= invn; pj *= invn; pk *= invn;

    // coalesced float2 stores: lane l covers out channels 2l, 2l+1
    float* ob = out + (size_t)pos * (4 * C_OUT);
    ((v2f*)(ob              ))[lane] = pr;
    ((v2f*)(ob +     C_OUT  ))[lane] = pi;
    ((v2f*)(ob + 2 * C_OUT  ))[lane] = pj;
    ((v2f*)(ob + 3 * C_OUT  ))[lane] = pk;
}

extern "C" void kernel_launch(void* const* d_in, const int* in_sizes, int n_in,
                              void* d_out, int out_size, void* d_ws, size_t ws_size,
                              hipStream_t stream) {
    const float* x      = (const float*)d_in[0];
    const float* weight = (const float*)d_in[1];
    const float* bias   = (const float*)d_in[2];
    float* out          = (float*)d_out;

    const int P = in_sizes[0] / (4 * C_IN);   // B*T = 2048
    const int grid = (P + POS_PER_BLOCK - 1) / POS_PER_BLOCK;

    qpu_kernel<<<grid, BLOCK, 0, stream>>>(x, weight, bias, out, P);
}